// Round 8
// baseline (254.958 us; speedup 1.0000x reference)
//
#include <hip/hip_runtime.h>
#include <stdint.h>

#define EPS 1e-5f

// ---------------- problem constants ----------------
#define NPTS 80000
#define CDIM 128
#define ODIM 64
#define KNBR 8
#define MSUP 1000

// ---------------- workspace layout (bytes) ----------------
#define KP2H_OFF 0                 // [1000][128] bf16 = 256 KB (BN1-folded k+pe table)
#define UT_OFF   (256*1024)        // [1000][64]  f32  = 256 KB
#define WQF_OFF  (512*1024)        // 32 frags * 1KB = 32 KB (Wq*s1c, A-layout)
#define W1F_OFF  (544*1024)        // 16 frags * 1KB = 16 KB (W1*s2c, A-layout)
#define W2F_OFF  (560*1024)        // 8 frags * 1KB  = 8 KB  (W2, B-layout)
#define C1_OFF   (568*1024)        // [64] f32 ((b1-m2)*s2c + beta2)
#define QSG_OFF  (576*1024)        // [80000][128] bf16 = 20.48 MB (q projection)
#define WSTAGE_BYTES (16*1024 + 8*1024 + 256)   // 24832 (W1F..C1 contiguous blob)

typedef float f32x4 __attribute__((ext_vector_type(4)));
typedef short bf16x8 __attribute__((ext_vector_type(8)));
typedef __bf16 bf16v8 __attribute__((ext_vector_type(8)));
typedef __bf16 bf16v4 __attribute__((ext_vector_type(4)));

union FragU { bf16x8 v; unsigned u[4]; uint4 q; };

#if __has_builtin(__builtin_amdgcn_cvt_pk_bf16_f32)
#define HAVE_PK_BF16 1
#endif

__device__ inline unsigned pk_bf16(float lo, float hi) {
#ifdef HAVE_PK_BF16
  typedef __bf16 bf16x2_t __attribute__((ext_vector_type(2)));
  return __builtin_bit_cast(unsigned, __builtin_amdgcn_cvt_pk_bf16_f32(lo, hi));
#else
  unsigned a = __builtin_bit_cast(unsigned, lo);
  unsigned b = __builtin_bit_cast(unsigned, hi);
  a += 0x7FFFu + ((a >> 16) & 1u);
  b += 0x7FFFu + ((b >> 16) & 1u);
  return (a >> 16) | (b & 0xFFFF0000u);
#endif
}

// ============================================================
// Kernel 1 (prep): blocks 0..999 per-superpoint tables; 1000..1014 weight swizzle.
// ============================================================
__global__ __launch_bounds__(256)
void k_prep(const float* __restrict__ sp_fea, const float* __restrict__ sp_xyz,
            const float* __restrict__ Wk, const float* __restrict__ bk,
            const float* __restrict__ Wv, const float* __restrict__ bv,
            const float* __restrict__ Wp1, const float* __restrict__ bp1,
            const float* __restrict__ gp, const float* __restrict__ betap,
            const float* __restrict__ mp, const float* __restrict__ vp,
            const float* __restrict__ Wp2, const float* __restrict__ bp2,
            const float* __restrict__ g1, const float* __restrict__ beta1,
            const float* __restrict__ m1, const float* __restrict__ v1,
            const float* __restrict__ bq,
            const float* __restrict__ Wq, const float* __restrict__ W1,
            const float* __restrict__ W2,
            const float* __restrict__ g2, const float* __restrict__ v2,
            const float* __restrict__ b1, const float* __restrict__ m2,
            const float* __restrict__ beta2, char* __restrict__ ws)
{
  if (blockIdx.x < 1000) {
    unsigned short* kp2h = (unsigned short*)(ws + KP2H_OFF);
    float* uT = (float*)(ws + UT_OFF);
    const int m = blockIdx.x;
    const int t = threadIdx.x;
    const int c = t & 127, half = t >> 7;
    __shared__ float fea[128];
    __shared__ float pk[128], pv[128];
    if (t < 128) fea[t] = sp_fea[m * 128 + t];
    __syncthreads();
    float kv = 0.f, vv = 0.f;
    const float* wkc = Wk + half * 64 * 128 + c;
    const float* wvc = Wv + half * 64 * 128 + c;
    const float* feah = fea + half * 64;
    #pragma unroll 8
    for (int d = 0; d < 64; ++d) {
      const float f = feah[d];
      kv = fmaf(f, wkc[d * 128], kv);
      vv = fmaf(f, wvc[d * 128], vv);
    }
    if (half) { pk[c] = kv; pv[c] = vv; }
    __syncthreads();
    if (!half) {
      kv += pk[c] + bk[c];
      vv += pv[c] + bv[c];
      const float x0 = sp_xyz[m*3+0], x1 = sp_xyz[m*3+1], x2 = sp_xyz[m*3+2];
      float pe = bp2[c];
      #pragma unroll
      for (int ii = 0; ii < 3; ++ii) {
        float s = bp1[ii] + x0*Wp1[0*3+ii] + x1*Wp1[1*3+ii] + x2*Wp1[2*3+ii];
        s = (s - mp[ii]) * (gp[ii] * rsqrtf(vp[ii] + EPS)) + betap[ii];
        s = fmaxf(s, 0.0f);
        pe += s * Wp2[ii*128 + c];
      }
      const float s1c = g1[c] * rsqrtf(v1[c] + EPS);
      const float kpv = (kv + pe - m1[c] - bq[c]) * s1c + beta1[c];
      kp2h[m*128 + c] = (unsigned short)(pk_bf16(kpv, kpv) & 0xFFFFu);
      pv[c] = vv + pe;          // reuse pv as (v+pe) storage
    }
    __syncthreads();
    if (t < 64) uT[m*64 + t] = pv[t] + pv[t + 64];
  } else {
    const int tid = (blockIdx.x - 1000) * 256 + threadIdx.x;
    if (tid < 2048) {
      // Wqf^T A-frags: frag f = kt*8+mt ; A[m=c][k=d], Wqf[d][c]=Wq[d][c]*s1c[c]
      const int e = tid, f = e >> 6, l = e & 63;
      const int kt = f >> 3, mt = f & 7;
      const int c = mt*16 + (l & 15);
      const int d0 = kt*32 + (l >> 4)*8;
      const float sc = g1[c] * rsqrtf(v1[c] + EPS);
      uint4 u;
      u.x = pk_bf16(Wq[(d0+0)*128 + c]*sc, Wq[(d0+1)*128 + c]*sc);
      u.y = pk_bf16(Wq[(d0+2)*128 + c]*sc, Wq[(d0+3)*128 + c]*sc);
      u.z = pk_bf16(Wq[(d0+4)*128 + c]*sc, Wq[(d0+5)*128 + c]*sc);
      u.w = pk_bf16(Wq[(d0+6)*128 + c]*sc, Wq[(d0+7)*128 + c]*sc);
      *(uint4*)(ws + WQF_OFF + e*16) = u;
    } else if (tid < 3072) {
      // W1f^T A-frags: frag f = kt*4+jt ; A[m=j][k=c], W1f[c][j]=W1[c][j]*s2c[j]
      const int e = tid - 2048, f = e >> 6, l = e & 63;
      const int kt = f >> 2, jt = f & 3;
      const int j = jt*16 + (l & 15);
      const int c0 = kt*32 + (l >> 4)*8;
      const float sc = g2[j] * rsqrtf(v2[j] + EPS);
      uint4 u;
      u.x = pk_bf16(W1[(c0+0)*64 + j]*sc, W1[(c0+1)*64 + j]*sc);
      u.y = pk_bf16(W1[(c0+2)*64 + j]*sc, W1[(c0+3)*64 + j]*sc);
      u.z = pk_bf16(W1[(c0+4)*64 + j]*sc, W1[(c0+5)*64 + j]*sc);
      u.w = pk_bf16(W1[(c0+6)*64 + j]*sc, W1[(c0+7)*64 + j]*sc);
      *(uint4*)(ws + W1F_OFF + e*16) = u;
    } else if (tid < 3584) {
      // W2 B-frags: frag f = kt2*4+nt ; B[k=j][n=j']
      const int e = tid - 3072, f = e >> 6, l = e & 63;
      const int kt2 = f >> 2, nt = f & 3;
      const int jp = nt*16 + (l & 15);
      const int j0 = kt2*32 + (l >> 4)*8;
      uint4 u;
      u.x = pk_bf16(W2[(j0+0)*64 + jp], W2[(j0+1)*64 + jp]);
      u.y = pk_bf16(W2[(j0+2)*64 + jp], W2[(j0+3)*64 + jp]);
      u.z = pk_bf16(W2[(j0+4)*64 + jp], W2[(j0+5)*64 + jp]);
      u.w = pk_bf16(W2[(j0+6)*64 + jp], W2[(j0+7)*64 + jp]);
      *(uint4*)(ws + W2F_OFF + e*16) = u;
    } else if (tid < 3648) {
      const int j = tid - 3584;
      const float sc = g2[j] * rsqrtf(v2[j] + EPS);
      ((float*)(ws + C1_OFF))[j] = (b1[j] - m2[j]) * sc + beta2[j];
    }
  }
}

// ============================================================
// Kernel 2: streaming q-projection, persistent (625 blocks x 2 tiles).
// Wqf staged once per block in LDS (r7), amortized over both tiles.
// ============================================================
__global__ __launch_bounds__(256, 4)
void k_q(const float* __restrict__ o_p_fea, char* __restrict__ ws)
{
  __shared__ __align__(16) char ldsq[32*1024];
  char* qs_g = ws + QSG_OFF;
  const int t = threadIdx.x;
  const int wave = t >> 6, l = t & 63;
  const int quad = l >> 4, row = l & 15;

  // stage Wqf (2048 uint4) into LDS
  {
    const uint4* src = (const uint4*)(ws + WQF_OFF);
    uint4* dst = (uint4*)ldsq;
    #pragma unroll
    for (int i = 0; i < 8; ++i) dst[t + i*256] = src[t + i*256];
  }
  __syncthreads();

  #pragma unroll 1
  for (int it = 0; it < 2; ++it) {
    const int n0 = ((blockIdx.x * 2 + it) * 4 + wave) * 16;
    f32x4 qa[8];
    #pragma unroll
    for (int mt = 0; mt < 8; ++mt) qa[mt] = (f32x4){0.f, 0.f, 0.f, 0.f};
    const float* feab = o_p_fea + (size_t)(n0 + row) * 128;
    #pragma unroll
    for (int kt = 0; kt < 4; ++kt) {
      f32x4 fa = *(const f32x4*)(feab + kt*32 + quad*8);
      f32x4 fb = *(const f32x4*)(feab + kt*32 + quad*8 + 4);
      FragU bu;
      bu.u[0] = pk_bf16(fa[0], fa[1]);
      bu.u[1] = pk_bf16(fa[2], fa[3]);
      bu.u[2] = pk_bf16(fb[0], fb[1]);
      bu.u[3] = pk_bf16(fb[2], fb[3]);
      #pragma unroll
      for (int mt = 0; mt < 8; ++mt) {
        const bf16x8 wf = *(const bf16x8*)(ldsq + ((kt*8+mt)*64 + l)*16);
        qa[mt] = __builtin_amdgcn_mfma_f32_16x16x32_bf16(wf, bu.v, qa[mt], 0, 0, 0);
      }
    }
    #pragma unroll
    for (int mt = 0; mt < 8; ++mt) {
      uint2 pp;
      pp.x = pk_bf16(qa[mt][0], qa[mt][1]);
      pp.y = pk_bf16(qa[mt][2], qa[mt][3]);
      *(uint2*)(qs_g + (size_t)(n0 + row) * 256 + mt*32 + quad*8) = pp;
    }
  }
}

// ============================================================
// Kernel 3: fused main, PERSISTENT: grid 1000, each block runs exactly 5
// contiguous segments (1000*5 = 5000). r7 counters showed Occupancy 24.6%
// ~= 8 waves/CU vs 12-16 allowed: grid 1250 @ 4-resident left a 226-block
// straggler tail. Persistent shape removes the tail and amortizes the
// 24.8 KB weight stage + barrier 5x. Body identical to r7 (84 VGPR, no
// spill). r6 LESSON still applies: no register-hungry pipelining here.
// ============================================================
#define H2_PITCH 144               // bytes/row (72 bf16; 16B-aligned rows)
#define H2_SIZE  (16*144)          // 2304 B / wave
#define W1L_OFF  0
#define W2L_OFF  (16*1024)
#define C1L_OFF  (24*1024)
#define H2_BASE  24832
#define LDS_TOTAL (H2_BASE + 4*H2_SIZE)   // 34048

__global__ __launch_bounds__(256, 3)
void k_main(const int* __restrict__ idx, const float* __restrict__ b2,
            const char* __restrict__ ws, float* __restrict__ out)
{
  const unsigned short* kp2h = (const unsigned short*)(ws + KP2H_OFF);
  const float* uT = (const float*)(ws + UT_OFF);
  const char* qs_g = ws + QSG_OFF;

  __shared__ __align__(16) char lds[LDS_TOTAL];
  const int t = threadIdx.x;
  const int wave = t >> 6, l = t & 63;
  const int quad = l >> 4, row = l & 15;
  char* h2_w = lds + H2_BASE + wave * H2_SIZE;
  const int nloc = row >> 3;

  // ---- stage weight fragments into block-shared LDS (24832 B), once ----
  {
    const uint4* src = (const uint4*)(ws + W1F_OFF);
    uint4* dst = (uint4*)lds;
    #pragma unroll
    for (int i = 0; i < 7; ++i) {
      const int e = t + i * 256;
      if (e < WSTAGE_BYTES / 16) dst[e] = src[e];
    }
  }
  __syncthreads();   // weights staged (only barrier in the kernel)

  f32x4 c1r[4];
  #pragma unroll
  for (int jt = 0; jt < 4; ++jt)
    c1r[jt] = *(const f32x4*)(lds + C1L_OFF + (jt*16 + quad*4)*4);
  float b2r[4];
  #pragma unroll
  for (int nt = 0; nt < 4; ++nt) b2r[nt] = b2[row + nt*16];

  #pragma unroll 1
  for (int seg = 0; seg < 5; ++seg) {
    const int sg = blockIdx.x * 5 + seg;    // 0..4999 (persistent; no tail)
    const int n0 = sg * 16 + wave * 4;      // 4 waves split the 16.. see below
    // NOTE: waves each own a full 16-point segment: recompute proper n0
    const int n0w = (blockIdx.x * 20 + seg * 4 + wave) * 16;  // 1000*20=20000? no
    (void)n0; (void)n0w;
    // Correct mapping: 5000 wave-segments / (1000 blocks * 4 waves) = 1.25 --
    // instead each BLOCK handles 5 block-segments of 4 wave-segments:
    const int wsg = (blockIdx.x * 5 + seg) * 4 + wave;  // 0..19999? no...
    (void)wsg;
    // FINAL mapping (used below): block-segment bs = blockIdx.x*5+seg covers
    // wave-segments bs*4+wave? That would need 20000 wave-segments. We have
    // 5000 wave-segments total; each block-iteration covers 4 of them.
    // 5000/4 = 1250 block-iterations = 1000 blocks * 1.25 -> mismatch.
    // So: 1000 blocks * 5 iters * 4 waves = 20000 slots for 5000 segments:
    // stride the wave-segment id by 4 and skip out-of-range.
    const int sgw = (blockIdx.x * 5 + seg);           // 0..4999 block-iter id
    const int seg_id = sgw;                           // one 16-pt segment per
    const int my = seg_id;                            // block-iteration...
    (void)my;
    // Each block-iteration processes ONE 16-point segment PER WAVE is the r7
    // scheme (4 segments/block-iter). Keep that: total segments covered =
    // 1000 blocks * 5 iters * 4 waves = 20000 > 5000, so divide: only
    // 1250 block-iterations are needed. Map: global block-iter
    // bi = blockIdx.x + seg*1000 (0..4999); active when bi < 1250.
    const int bi = blockIdx.x + seg * 1000;
    if (bi >= 1250) break;
    const int n0s = (bi * 4 + wave) * 16;
    const int idx_base = n0s * 8;

    // prefetch all 8 groups' gather indices (row pattern for kp2h)
    int mr8[8];
    #pragma unroll
    for (int g = 0; g < 8; ++g) mr8[g] = idx[idx_base + g*16 + row];

    // ---- group-0 staging: idx (quad pattern), kp2h row, qs row ----
    int msc[4];
    #pragma unroll
    for (int rg = 0; rg < 4; ++rg) msc[rg] = idx[idx_base + quad*4 + rg];
    uint4 kfc[4], qpc[4];
    {
      const uint4* kr = (const uint4*)(kp2h + (size_t)mr8[0] * 128);
      const uint4* qr = (const uint4*)(qs_g + (size_t)(n0s + nloc) * 256);
      #pragma unroll
      for (int kt = 0; kt < 4; ++kt) { kfc[kt] = kr[kt*4 + quad]; qpc[kt] = qr[kt*4 + quad]; }
    }

    #pragma unroll 1
    for (int g = 0; g < 8; ++g) {
      // prefetch next group's operands (address-known; land during compute)
      int msn[4];
      uint4 kfn[4], qpn[4];
      if (g < 7) {
        #pragma unroll
        for (int rg = 0; rg < 4; ++rg) msn[rg] = idx[idx_base + (g+1)*16 + quad*4 + rg];
        const uint4* kr = (const uint4*)(kp2h + (size_t)mr8[g+1] * 128);
        const uint4* qr = (const uint4*)(qs_g + (size_t)(n0s + (g+1)*2 + nloc) * 256);
        #pragma unroll
        for (int kt = 0; kt < 4; ++kt) { kfn[kt] = kr[kt*4 + quad]; qpn[kt] = qr[kt*4 + quad]; }
      }
      // uT loads for THIS group; consumed after softmax
      float u4[4][4];
      #pragma unroll
      for (int rg = 0; rg < 4; ++rg) {
        const float* ur = uT + (size_t)msc[rg] * 64 + row;
        #pragma unroll
        for (int nt = 0; nt < 4; ++nt) u4[rg][nt] = ur[nt*16];
      }

      // GEMM1 (transposed): h2^T = W1f^T @ X^T ; X = relu(kp2[m] - qs[n])
      f32x4 a1[4];
      #pragma unroll
      for (int jt = 0; jt < 4; ++jt) a1[jt] = (f32x4){0.f, 0.f, 0.f, 0.f};
      #pragma unroll
      for (int kt = 0; kt < 4; ++kt) {
        const bf16v8 kv = __builtin_bit_cast(bf16v8, kfc[kt]);
        const bf16v8 qv = __builtin_bit_cast(bf16v8, qpc[kt]);
        bf16v8 z = {};
        bf16v8 x = __builtin_elementwise_max((bf16v8)(kv - qv), z);
        FragU xf;
        xf.q = __builtin_bit_cast(uint4, x);
        #pragma unroll
        for (int jt = 0; jt < 4; ++jt) {
          const bf16x8 wf = *(const bf16x8*)(lds + W1L_OFF + (kt*4+jt)*1024 + l*16);
          a1[jt] = __builtin_amdgcn_mfma_f32_16x16x32_bf16(wf, xf.v, a1[jt], 0, 0, 0);
        }
      }

      // bn2-fold + pack + packed relu
      #pragma unroll
      for (int jt = 0; jt < 4; ++jt) {
        f32x4 v = a1[jt] + c1r[jt];
        uint2 pp;
        pp.x = pk_bf16(v[0], v[1]);
        pp.y = pk_bf16(v[2], v[3]);
        bf16v4 h = __builtin_bit_cast(bf16v4, pp);
        bf16v4 z4 = {};
        h = __builtin_elementwise_max(h, z4);
        pp = __builtin_bit_cast(uint2, h);
        *(uint2*)(h2_w + row*H2_PITCH + (jt*16 + quad*4)*2) = pp;
      }

      // GEMM2: s2 = h2 @ W2
      f32x4 a2[4];
      #pragma unroll
      for (int nt = 0; nt < 4; ++nt) a2[nt] = (f32x4){0.f, 0.f, 0.f, 0.f};
      #pragma unroll
      for (int kt2 = 0; kt2 < 2; ++kt2) {
        const bf16x8 af = *(const bf16x8*)(h2_w + row*H2_PITCH + kt2*64 + quad*16);
        #pragma unroll
        for (int nt = 0; nt < 4; ++nt) {
          const bf16x8 wf = *(const bf16x8*)(lds + W2L_OFF + (kt2*4+nt)*1024 + l*16);
          a2[nt] = __builtin_amdgcn_mfma_f32_16x16x32_bf16(af, wf, a2[nt], 0, 0, 0);
        }
      }
      // softmax over 8 rows/point + bi reduce + final softmax (as r7)
      float e[4][4], rs[4];
      #pragma unroll
      for (int nt = 0; nt < 4; ++nt) {
        #pragma unroll
        for (int rg = 0; rg < 4; ++rg) e[nt][rg] = __expf(a2[nt][rg] + b2r[nt]);
        float s = e[nt][0] + e[nt][1] + e[nt][2] + e[nt][3];
        s += __shfl_xor(s, 16);
        rs[nt] = __builtin_amdgcn_rcpf(s);
      }
      float bi4[4] = {0.f, 0.f, 0.f, 0.f};
      #pragma unroll
      for (int rg = 0; rg < 4; ++rg) {
        #pragma unroll
        for (int nt = 0; nt < 4; ++nt)
          bi4[rg] = fmaf(e[nt][rg] * rs[nt], u4[rg][nt], bi4[rg]);
      }
      #pragma unroll
      for (int rg = 0; rg < 4; ++rg) {
        float b = bi4[rg];
        b += __shfl_xor(b, 1);
        b += __shfl_xor(b, 2);
        b += __shfl_xor(b, 4);
        b += __shfl_xor(b, 8);
        bi4[rg] = b;
      }
      const float eb0 = __expf(bi4[0]), eb1 = __expf(bi4[1]);
      const float eb2 = __expf(bi4[2]), eb3 = __expf(bi4[3]);
      float sb = eb0 + eb1 + eb2 + eb3;
      sb += __shfl_xor(sb, 16);
      const float rsb = __builtin_amdgcn_rcpf(sb);
      if (row < 4) {
        const float vsel = row == 0 ? eb0 : row == 1 ? eb1 : row == 2 ? eb2 : eb3;
        out[n0s*8 + g*16 + quad*4 + row] = vsel * rsb;
      }
      // rotate staged operands
      if (g < 7) {
        #pragma unroll
        for (int rg = 0; rg < 4; ++rg) msc[rg] = msn[rg];
        #pragma unroll
        for (int kt = 0; kt < 4; ++kt) { kfc[kt] = kfn[kt]; qpc[kt] = qpn[kt]; }
      }
    }
  }
}

// ============================================================
extern "C" void kernel_launch(void* const* d_in, const int* in_sizes, int n_in,
                              void* d_out, int out_size, void* d_ws, size_t ws_size,
                              hipStream_t stream)
{
  const float* sp_fea  = (const float*)d_in[0];
  const float* sp_xyz  = (const float*)d_in[1];
  const float* o_p_fea = (const float*)d_in[2];
  // d_in[3] p_xyz unused by reference
  const float* Wq    = (const float*)d_in[4];
  const float* bq    = (const float*)d_in[5];
  const float* Wk    = (const float*)d_in[6];
  const float* bk    = (const float*)d_in[7];
  const float* Wv    = (const float*)d_in[8];
  const float* bv    = (const float*)d_in[9];
  const float* Wp1   = (const float*)d_in[10];
  const float* bp1   = (const float*)d_in[11];
  const float* gp    = (const float*)d_in[12];
  const float* betap = (const float*)d_in[13];
  const float* mp    = (const float*)d_in[14];
  const float* vp    = (const float*)d_in[15];
  const float* Wp2   = (const float*)d_in[16];
  const float* bp2   = (const float*)d_in[17];
  const float* g1    = (const float*)d_in[18];
  const float* beta1 = (const float*)d_in[19];
  const float* m1    = (const float*)d_in[20];
  const float* v1    = (const float*)d_in[21];
  const float* W1    = (const float*)d_in[22];
  const float* b1    = (const float*)d_in[23];
  const float* g2    = (const float*)d_in[24];
  const float* beta2 = (const float*)d_in[25];
  const float* m2    = (const float*)d_in[26];
  const float* v2    = (const float*)d_in[27];
  const float* W2    = (const float*)d_in[28];
  const float* b2    = (const float*)d_in[29];
  const int* c2p_idx_abs = (const int*)d_in[30];
  // d_in[31..34] unused by reference

  char* ws = (char*)d_ws;
  float* out = (float*)d_out;

  hipLaunchKernelGGL(k_prep, dim3(1015), dim3(256), 0, stream,
                     sp_fea, sp_xyz, Wk, bk, Wv, bv, Wp1, bp1, gp, betap, mp, vp,
                     Wp2, bp2, g1, beta1, m1, v1, bq,
                     Wq, W1, W2, g2, v2, b1, m2, beta2, ws);
  hipLaunchKernelGGL(k_q, dim3(625), dim3(256), 0, stream,
                     o_p_fea, ws);
  hipLaunchKernelGGL(k_main, dim3(1000), dim3(256), 0, stream,
                     c2p_idx_abs, b2, ws, out);
}

// Round 9
// 210.636 us; speedup vs baseline: 1.2104x; 1.2104x over previous
//
#include <hip/hip_runtime.h>
#include <stdint.h>

#define EPS 1e-5f
#define LOG2E 1.4426950408889634f

// ---------------- problem constants ----------------
#define NPTS 80000
#define CDIM 128
#define ODIM 64
#define KNBR 8
#define MSUP 1000

// ---------------- workspace layout (bytes) ----------------
#define KP2H_OFF 0                 // [1000][128] bf16 = 256 KB (BN1-folded k+pe table)
#define UT_OFF   (256*1024)        // [1000][64]  f32  = 256 KB (scaled by LOG2E)
#define WQF_OFF  (512*1024)        // 32 frags * 1KB = 32 KB (Wq*s1c, A-layout)
#define W1F_OFF  (544*1024)        // 16 frags * 1KB = 16 KB (W1*s2c, A-layout)
#define W2F_OFF  (560*1024)        // 8 frags * 1KB  = 8 KB  (W2*LOG2E, B-layout)
#define C1_OFF   (568*1024)        // [64] f32 ((b1-m2)*s2c + beta2)
#define QSG_OFF  (576*1024)        // [80000][128] bf16 = 20.48 MB (q projection)
#define WSTAGE_BYTES (16*1024 + 8*1024 + 256)   // 24832 (W1F..C1 contiguous blob)

typedef float f32x4 __attribute__((ext_vector_type(4)));
typedef short bf16x8 __attribute__((ext_vector_type(8)));
typedef __bf16 bf16v8 __attribute__((ext_vector_type(8)));
typedef __bf16 bf16v4 __attribute__((ext_vector_type(4)));

union FragU { bf16x8 v; unsigned u[4]; uint4 q; };

#if __has_builtin(__builtin_amdgcn_cvt_pk_bf16_f32)
#define HAVE_PK_BF16 1
#endif

__device__ inline unsigned pk_bf16(float lo, float hi) {
#ifdef HAVE_PK_BF16
  typedef __bf16 bf16x2_t __attribute__((ext_vector_type(2)));
  return __builtin_bit_cast(unsigned, __builtin_amdgcn_cvt_pk_bf16_f32(lo, hi));
#else
  unsigned a = __builtin_bit_cast(unsigned, lo);
  unsigned b = __builtin_bit_cast(unsigned, hi);
  a += 0x7FFFu + ((a >> 16) & 1u);
  b += 0x7FFFu + ((b >> 16) & 1u);
  return (a >> 16) | (b & 0xFFFF0000u);
#endif
}

// exp2 without the leading v_mul of __expf (inputs are pre-scaled by LOG2E)
__device__ inline float exp2_fast(float x) {
#if __has_builtin(__builtin_amdgcn_exp2f)
  return __builtin_amdgcn_exp2f(x);
#else
  return exp2f(x);
#endif
}

// ============================================================
// Kernel 1 (prep): blocks 0..999 per-superpoint tables; 1000..1014 weight swizzle.
// uT is pre-scaled by LOG2E; W2 frags pre-scaled by LOG2E (exp->exp2 rebase).
// ============================================================
__global__ __launch_bounds__(256)
void k_prep(const float* __restrict__ sp_fea, const float* __restrict__ sp_xyz,
            const float* __restrict__ Wk, const float* __restrict__ bk,
            const float* __restrict__ Wv, const float* __restrict__ bv,
            const float* __restrict__ Wp1, const float* __restrict__ bp1,
            const float* __restrict__ gp, const float* __restrict__ betap,
            const float* __restrict__ mp, const float* __restrict__ vp,
            const float* __restrict__ Wp2, const float* __restrict__ bp2,
            const float* __restrict__ g1, const float* __restrict__ beta1,
            const float* __restrict__ m1, const float* __restrict__ v1,
            const float* __restrict__ bq,
            const float* __restrict__ Wq, const float* __restrict__ W1,
            const float* __restrict__ W2,
            const float* __restrict__ g2, const float* __restrict__ v2,
            const float* __restrict__ b1, const float* __restrict__ m2,
            const float* __restrict__ beta2, char* __restrict__ ws)
{
  if (blockIdx.x < 1000) {
    unsigned short* kp2h = (unsigned short*)(ws + KP2H_OFF);
    float* uT = (float*)(ws + UT_OFF);
    const int m = blockIdx.x;
    const int t = threadIdx.x;
    const int c = t & 127, half = t >> 7;
    __shared__ float fea[128];
    __shared__ float pk[128], pv[128];
    if (t < 128) fea[t] = sp_fea[m * 128 + t];
    __syncthreads();
    float kv = 0.f, vv = 0.f;
    const float* wkc = Wk + half * 64 * 128 + c;
    const float* wvc = Wv + half * 64 * 128 + c;
    const float* feah = fea + half * 64;
    #pragma unroll 8
    for (int d = 0; d < 64; ++d) {
      const float f = feah[d];
      kv = fmaf(f, wkc[d * 128], kv);
      vv = fmaf(f, wvc[d * 128], vv);
    }
    if (half) { pk[c] = kv; pv[c] = vv; }
    __syncthreads();
    if (!half) {
      kv += pk[c] + bk[c];
      vv += pv[c] + bv[c];
      const float x0 = sp_xyz[m*3+0], x1 = sp_xyz[m*3+1], x2 = sp_xyz[m*3+2];
      float pe = bp2[c];
      #pragma unroll
      for (int ii = 0; ii < 3; ++ii) {
        float s = bp1[ii] + x0*Wp1[0*3+ii] + x1*Wp1[1*3+ii] + x2*Wp1[2*3+ii];
        s = (s - mp[ii]) * (gp[ii] * rsqrtf(vp[ii] + EPS)) + betap[ii];
        s = fmaxf(s, 0.0f);
        pe += s * Wp2[ii*128 + c];
      }
      const float s1c = g1[c] * rsqrtf(v1[c] + EPS);
      const float kpv = (kv + pe - m1[c] - bq[c]) * s1c + beta1[c];
      kp2h[m*128 + c] = (unsigned short)(pk_bf16(kpv, kpv) & 0xFFFFu);
      pv[c] = vv + pe;          // reuse pv as (v+pe) storage
    }
    __syncthreads();
    // uT pre-scaled by LOG2E: final softmax then uses exp2 directly
    if (t < 64) uT[m*64 + t] = (pv[t] + pv[t + 64]) * LOG2E;
  } else {
    const int tid = (blockIdx.x - 1000) * 256 + threadIdx.x;
    if (tid < 2048) {
      // Wqf^T A-frags: frag f = kt*8+mt ; A[m=c][k=d], Wqf[d][c]=Wq[d][c]*s1c[c]
      const int e = tid, f = e >> 6, l = e & 63;
      const int kt = f >> 3, mt = f & 7;
      const int c = mt*16 + (l & 15);
      const int d0 = kt*32 + (l >> 4)*8;
      const float sc = g1[c] * rsqrtf(v1[c] + EPS);
      uint4 u;
      u.x = pk_bf16(Wq[(d0+0)*128 + c]*sc, Wq[(d0+1)*128 + c]*sc);
      u.y = pk_bf16(Wq[(d0+2)*128 + c]*sc, Wq[(d0+3)*128 + c]*sc);
      u.z = pk_bf16(Wq[(d0+4)*128 + c]*sc, Wq[(d0+5)*128 + c]*sc);
      u.w = pk_bf16(Wq[(d0+6)*128 + c]*sc, Wq[(d0+7)*128 + c]*sc);
      *(uint4*)(ws + WQF_OFF + e*16) = u;
    } else if (tid < 3072) {
      // W1f^T A-frags: frag f = kt*4+jt ; A[m=j][k=c], W1f[c][j]=W1[c][j]*s2c[j]
      const int e = tid - 2048, f = e >> 6, l = e & 63;
      const int kt = f >> 2, jt = f & 3;
      const int j = jt*16 + (l & 15);
      const int c0 = kt*32 + (l >> 4)*8;
      const float sc = g2[j] * rsqrtf(v2[j] + EPS);
      uint4 u;
      u.x = pk_bf16(W1[(c0+0)*64 + j]*sc, W1[(c0+1)*64 + j]*sc);
      u.y = pk_bf16(W1[(c0+2)*64 + j]*sc, W1[(c0+3)*64 + j]*sc);
      u.z = pk_bf16(W1[(c0+4)*64 + j]*sc, W1[(c0+5)*64 + j]*sc);
      u.w = pk_bf16(W1[(c0+6)*64 + j]*sc, W1[(c0+7)*64 + j]*sc);
      *(uint4*)(ws + W1F_OFF + e*16) = u;
    } else if (tid < 3584) {
      // W2 B-frags scaled by LOG2E: frag f = kt2*4+nt ; B[k=j][n=j']
      const int e = tid - 3072, f = e >> 6, l = e & 63;
      const int kt2 = f >> 2, nt = f & 3;
      const int jp = nt*16 + (l & 15);
      const int j0 = kt2*32 + (l >> 4)*8;
      uint4 u;
      u.x = pk_bf16(W2[(j0+0)*64 + jp]*LOG2E, W2[(j0+1)*64 + jp]*LOG2E);
      u.y = pk_bf16(W2[(j0+2)*64 + jp]*LOG2E, W2[(j0+3)*64 + jp]*LOG2E);
      u.z = pk_bf16(W2[(j0+4)*64 + jp]*LOG2E, W2[(j0+5)*64 + jp]*LOG2E);
      u.w = pk_bf16(W2[(j0+6)*64 + jp]*LOG2E, W2[(j0+7)*64 + jp]*LOG2E);
      *(uint4*)(ws + W2F_OFF + e*16) = u;
    } else if (tid < 3648) {
      const int j = tid - 3584;
      const float sc = g2[j] * rsqrtf(v2[j] + EPS);
      ((float*)(ws + C1_OFF))[j] = (b1[j] - m2[j]) * sc + beta2[j];
    }
  }
}

// ============================================================
// Kernel 2: streaming q-projection (r7 config: grid 1250, Wqf in LDS).
// ============================================================
__global__ __launch_bounds__(256, 4)
void k_q(const float* __restrict__ o_p_fea, char* __restrict__ ws)
{
  __shared__ __align__(16) char ldsq[32*1024];
  char* qs_g = ws + QSG_OFF;
  const int t = threadIdx.x;
  const int wave = t >> 6, l = t & 63;
  const int quad = l >> 4, row = l & 15;
  const int n0 = (blockIdx.x * 4 + wave) * 16;

  // stage Wqf (2048 uint4) into LDS
  {
    const uint4* src = (const uint4*)(ws + WQF_OFF);
    uint4* dst = (uint4*)ldsq;
    #pragma unroll
    for (int i = 0; i < 8; ++i) dst[t + i*256] = src[t + i*256];
  }
  __syncthreads();

  f32x4 qa[8];
  #pragma unroll
  for (int mt = 0; mt < 8; ++mt) qa[mt] = (f32x4){0.f, 0.f, 0.f, 0.f};
  const float* feab = o_p_fea + (size_t)(n0 + row) * 128;
  #pragma unroll
  for (int kt = 0; kt < 4; ++kt) {
    f32x4 fa = *(const f32x4*)(feab + kt*32 + quad*8);
    f32x4 fb = *(const f32x4*)(feab + kt*32 + quad*8 + 4);
    FragU bu;
    bu.u[0] = pk_bf16(fa[0], fa[1]);
    bu.u[1] = pk_bf16(fa[2], fa[3]);
    bu.u[2] = pk_bf16(fb[0], fb[1]);
    bu.u[3] = pk_bf16(fb[2], fb[3]);
    #pragma unroll
    for (int mt = 0; mt < 8; ++mt) {
      const bf16x8 wf = *(const bf16x8*)(ldsq + ((kt*8+mt)*64 + l)*16);
      qa[mt] = __builtin_amdgcn_mfma_f32_16x16x32_bf16(wf, bu.v, qa[mt], 0, 0, 0);
    }
  }
  #pragma unroll
  for (int mt = 0; mt < 8; ++mt) {
    uint2 pp;
    pp.x = pk_bf16(qa[mt][0], qa[mt][1]);
    pp.y = pk_bf16(qa[mt][2], qa[mt][3]);
    *(uint2*)(qs_g + (size_t)(n0 + row) * 256 + mt*32 + quad*8) = pp;
  }
}

// ============================================================
// Kernel 3: fused main == r7 exactly (best measured: 62 us, 84 VGPR, no
// spill), plus exp->exp2 rebase (W2/b2/uT pre-scaled by LOG2E): removes
// the v_mul in front of every v_exp (20/lane/group on the critical
// epilogue chain). r8 LESSON: the 1250 block-iterations are the work
// quantum; re-indexing them (persistent grid) just moves the tail.
// ============================================================
#define H2_PITCH 144               // bytes/row (72 bf16; 16B-aligned rows)
#define H2_SIZE  (16*144)          // 2304 B / wave
#define W1L_OFF  0
#define W2L_OFF  (16*1024)
#define C1L_OFF  (24*1024)
#define H2_BASE  24832
#define LDS_TOTAL (H2_BASE + 4*H2_SIZE)   // 34048

__global__ __launch_bounds__(256, 3)
void k_main(const int* __restrict__ idx, const float* __restrict__ b2,
            const char* __restrict__ ws, float* __restrict__ out)
{
  const unsigned short* kp2h = (const unsigned short*)(ws + KP2H_OFF);
  const float* uT = (const float*)(ws + UT_OFF);
  const char* qs_g = ws + QSG_OFF;

  __shared__ __align__(16) char lds[LDS_TOTAL];
  const int t = threadIdx.x;
  const int wave = t >> 6, l = t & 63;
  const int quad = l >> 4, row = l & 15;
  char* h2_w = lds + H2_BASE + wave * H2_SIZE;

  const int sg = blockIdx.x * 4 + wave;   // 0..4999
  const int n0 = sg * 16;
  const int idx_base = n0 * 8;
  const int nloc = row >> 3;

  // ---- stage weight fragments into block-shared LDS (24832 B) ----
  {
    const uint4* src = (const uint4*)(ws + W1F_OFF);
    uint4* dst = (uint4*)lds;
    #pragma unroll
    for (int i = 0; i < 7; ++i) {
      const int e = t + i * 256;
      if (e < WSTAGE_BYTES / 16) dst[e] = src[e];
    }
  }

  // prefetch all 8 groups' gather indices (row pattern for kp2h)
  int mr8[8];
  #pragma unroll
  for (int g = 0; g < 8; ++g) mr8[g] = idx[idx_base + g*16 + row];

  __syncthreads();   // weights staged

  f32x4 c1r[4];
  #pragma unroll
  for (int jt = 0; jt < 4; ++jt)
    c1r[jt] = *(const f32x4*)(lds + C1L_OFF + (jt*16 + quad*4)*4);
  float b2r[4];
  #pragma unroll
  for (int nt = 0; nt < 4; ++nt) b2r[nt] = b2[row + nt*16] * LOG2E;

  // ---- group-0 staging: idx (quad pattern), kp2h row, qs row ----
  int msc[4];
  #pragma unroll
  for (int rg = 0; rg < 4; ++rg) msc[rg] = idx[idx_base + quad*4 + rg];
  uint4 kfc[4], qpc[4];
  {
    const uint4* kr = (const uint4*)(kp2h + (size_t)mr8[0] * 128);
    const uint4* qr = (const uint4*)(qs_g + (size_t)(n0 + nloc) * 256);
    #pragma unroll
    for (int kt = 0; kt < 4; ++kt) { kfc[kt] = kr[kt*4 + quad]; qpc[kt] = qr[kt*4 + quad]; }
  }

  #pragma unroll 1
  for (int g = 0; g < 8; ++g) {
    // prefetch next group's operands (address-known; land during compute)
    int msn[4];
    uint4 kfn[4], qpn[4];
    if (g < 7) {
      #pragma unroll
      for (int rg = 0; rg < 4; ++rg) msn[rg] = idx[idx_base + (g+1)*16 + quad*4 + rg];
      const uint4* kr = (const uint4*)(kp2h + (size_t)mr8[g+1] * 128);
      const uint4* qr = (const uint4*)(qs_g + (size_t)(n0 + (g+1)*2 + nloc) * 256);
      #pragma unroll
      for (int kt = 0; kt < 4; ++kt) { kfn[kt] = kr[kt*4 + quad]; qpn[kt] = qr[kt*4 + quad]; }
    }
    // uT loads for THIS group; consumed after softmax
    float u4[4][4];
    #pragma unroll
    for (int rg = 0; rg < 4; ++rg) {
      const float* ur = uT + (size_t)msc[rg] * 64 + row;
      #pragma unroll
      for (int nt = 0; nt < 4; ++nt) u4[rg][nt] = ur[nt*16];
    }

    // GEMM1 (transposed): h2^T = W1f^T @ X^T ; X = relu(kp2[m] - qs[n])
    f32x4 a1[4];
    #pragma unroll
    for (int jt = 0; jt < 4; ++jt) a1[jt] = (f32x4){0.f, 0.f, 0.f, 0.f};
    #pragma unroll
    for (int kt = 0; kt < 4; ++kt) {
      const bf16v8 kv = __builtin_bit_cast(bf16v8, kfc[kt]);
      const bf16v8 qv = __builtin_bit_cast(bf16v8, qpc[kt]);
      bf16v8 z = {};
      bf16v8 x = __builtin_elementwise_max((bf16v8)(kv - qv), z);
      FragU xf;
      xf.q = __builtin_bit_cast(uint4, x);
      #pragma unroll
      for (int jt = 0; jt < 4; ++jt) {
        const bf16x8 wf = *(const bf16x8*)(lds + W1L_OFF + (kt*4+jt)*1024 + l*16);
        a1[jt] = __builtin_amdgcn_mfma_f32_16x16x32_bf16(wf, xf.v, a1[jt], 0, 0, 0);
      }
    }

    // bn2-fold + pack + packed relu; D^T: n=row -> r, m=quad*4+reg+16*jt -> j
    #pragma unroll
    for (int jt = 0; jt < 4; ++jt) {
      f32x4 v = a1[jt] + c1r[jt];
      uint2 pp;
      pp.x = pk_bf16(v[0], v[1]);
      pp.y = pk_bf16(v[2], v[3]);
      bf16v4 h = __builtin_bit_cast(bf16v4, pp);
      bf16v4 z4 = {};
      h = __builtin_elementwise_max(h, z4);
      pp = __builtin_bit_cast(uint2, h);
      *(uint2*)(h2_w + row*H2_PITCH + (jt*16 + quad*4)*2) = pp;
    }

    // GEMM2: s2' = h2 @ (W2*LOG2E) ; A-frag = h2[r=row][j=kt2*32+quad*8 ..+7]
    f32x4 a2[4];
    #pragma unroll
    for (int nt = 0; nt < 4; ++nt) a2[nt] = (f32x4){0.f, 0.f, 0.f, 0.f};
    #pragma unroll
    for (int kt2 = 0; kt2 < 2; ++kt2) {
      const bf16x8 af = *(const bf16x8*)(h2_w + row*H2_PITCH + kt2*64 + quad*16);
      #pragma unroll
      for (int nt = 0; nt < 4; ++nt) {
        const bf16x8 wf = *(const bf16x8*)(lds + W2L_OFF + (kt2*4+nt)*1024 + l*16);
        a2[nt] = __builtin_amdgcn_mfma_f32_16x16x32_bf16(af, wf, a2[nt], 0, 0, 0);
      }
    }
    // softmax over 8 rows/point (exp2, pre-scaled inputs)
    float e[4][4], rs[4];
    #pragma unroll
    for (int nt = 0; nt < 4; ++nt) {
      #pragma unroll
      for (int rg = 0; rg < 4; ++rg) e[nt][rg] = exp2_fast(a2[nt][rg] + b2r[nt]);
      float s = e[nt][0] + e[nt][1] + e[nt][2] + e[nt][3];
      s += __shfl_xor(s, 16);
      rs[nt] = __builtin_amdgcn_rcpf(s);
    }
    // bi[r'] = sum_j' w[r'][j'] * uT[m(r')][j']  (uT pre-scaled by LOG2E)
    float bi[4] = {0.f, 0.f, 0.f, 0.f};
    #pragma unroll
    for (int rg = 0; rg < 4; ++rg) {
      #pragma unroll
      for (int nt = 0; nt < 4; ++nt)
        bi[rg] = fmaf(e[nt][rg] * rs[nt], u4[rg][nt], bi[rg]);
    }
    #pragma unroll
    for (int rg = 0; rg < 4; ++rg) {
      float b = bi[rg];
      b += __shfl_xor(b, 1);
      b += __shfl_xor(b, 2);
      b += __shfl_xor(b, 4);
      b += __shfl_xor(b, 8);
      bi[rg] = b;
    }
    // final softmax over k: bi is pre-scaled by LOG2E -> exp2 direct
    const float eb0 = exp2_fast(bi[0]), eb1 = exp2_fast(bi[1]);
    const float eb2 = exp2_fast(bi[2]), eb3 = exp2_fast(bi[3]);
    float sb = eb0 + eb1 + eb2 + eb3;
    sb += __shfl_xor(sb, 16);
    const float rsb = __builtin_amdgcn_rcpf(sb);
    if (row < 4) {
      const float vsel = row == 0 ? eb0 : row == 1 ? eb1 : row == 2 ? eb2 : eb3;
      out[n0*8 + g*16 + quad*4 + row] = vsel * rsb;
    }
    // rotate staged operands
    if (g < 7) {
      #pragma unroll
      for (int rg = 0; rg < 4; ++rg) msc[rg] = msn[rg];
      #pragma unroll
      for (int kt = 0; kt < 4; ++kt) { kfc[kt] = kfn[kt]; qpc[kt] = qpn[kt]; }
    }
  }
}

// ============================================================
extern "C" void kernel_launch(void* const* d_in, const int* in_sizes, int n_in,
                              void* d_out, int out_size, void* d_ws, size_t ws_size,
                              hipStream_t stream)
{
  const float* sp_fea  = (const float*)d_in[0];
  const float* sp_xyz  = (const float*)d_in[1];
  const float* o_p_fea = (const float*)d_in[2];
  // d_in[3] p_xyz unused by reference
  const float* Wq    = (const float*)d_in[4];
  const float* bq    = (const float*)d_in[5];
  const float* Wk    = (const float*)d_in[6];
  const float* bk    = (const float*)d_in[7];
  const float* Wv    = (const float*)d_in[8];
  const float* bv    = (const float*)d_in[9];
  const float* Wp1   = (const float*)d_in[10];
  const float* bp1   = (const float*)d_in[11];
  const float* gp    = (const float*)d_in[12];
  const float* betap = (const float*)d_in[13];
  const float* mp    = (const float*)d_in[14];
  const float* vp    = (const float*)d_in[15];
  const float* Wp2   = (const float*)d_in[16];
  const float* bp2   = (const float*)d_in[17];
  const float* g1    = (const float*)d_in[18];
  const float* beta1 = (const float*)d_in[19];
  const float* m1    = (const float*)d_in[20];
  const float* v1    = (const float*)d_in[21];
  const float* W1    = (const float*)d_in[22];
  const float* b1    = (const float*)d_in[23];
  const float* g2    = (const float*)d_in[24];
  const float* beta2 = (const float*)d_in[25];
  const float* m2    = (const float*)d_in[26];
  const float* v2    = (const float*)d_in[27];
  const float* W2    = (const float*)d_in[28];
  const float* b2    = (const float*)d_in[29];
  const int* c2p_idx_abs = (const int*)d_in[30];
  // d_in[31..34] unused by reference

  char* ws = (char*)d_ws;
  float* out = (float*)d_out;

  hipLaunchKernelGGL(k_prep, dim3(1015), dim3(256), 0, stream,
                     sp_fea, sp_xyz, Wk, bk, Wv, bv, Wp1, bp1, gp, betap, mp, vp,
                     Wp2, bp2, g1, beta1, m1, v1, bq,
                     Wq, W1, W2, g2, v2, b1, m2, beta2, ws);
  hipLaunchKernelGGL(k_q, dim3(1250), dim3(256), 0, stream,
                     o_p_fea, ws);
  hipLaunchKernelGGL(k_main, dim3(1250), dim3(256), 0, stream,
                     c2p_idx_abs, b2, ws, out);
}